// Round 9
// baseline (235.504 us; speedup 1.0000x reference)
//
#include <hip/hip_runtime.h>
#include <math.h>

#define D_MODEL 768
#define NUM_HEADS 12
#define HEAD_DIM 64
#define SEQ 2048
#define BATCH 4
#define MROWS (BATCH * SEQ)   // 8192
#define HALF_D (D_MODEL / 2)  // 384

typedef __bf16    bf16x8 __attribute__((ext_vector_type(8)));
typedef _Float16  f16x4  __attribute__((ext_vector_type(4)));
typedef float     f32x4  __attribute__((ext_vector_type(4)));

// async global->LDS, 16B per lane; LDS dest = wave-uniform base + lane*16
__device__ __forceinline__ void gload_lds16(const void* gp, void* lp) {
    __builtin_amdgcn_global_load_lds(
        (const __attribute__((address_space(1))) unsigned int*)gp,
        (__attribute__((address_space(3))) unsigned int*)lp, 16, 0, 0);
}

// ---------------------------------------------------------------------------
// prep: X cast (blocks [0,3072)) + weight cast/transpose ([3072,3648)).
// ---------------------------------------------------------------------------
__global__ __launch_bounds__(256)
void prep(const float* __restrict__ X, __bf16* __restrict__ Xb,
          const float* __restrict__ W0, const float* __restrict__ W1,
          const float* __restrict__ W2, const float* __restrict__ W3,
          __bf16* __restrict__ T0, __bf16* __restrict__ T1,
          __bf16* __restrict__ T2, __bf16* __restrict__ T3)
{
    __shared__ float t[64][65];
    const int n   = blockIdx.x;
    const int tid = threadIdx.x;

    if (n < 3072) {
        size_t i = ((size_t)n * 256 + tid) * 8;
        float4 u = *(const float4*)(X + i);
        float4 v = *(const float4*)(X + i + 4);
        bf16x8 o;
        o[0]=(__bf16)u.x; o[1]=(__bf16)u.y; o[2]=(__bf16)u.z; o[3]=(__bf16)u.w;
        o[4]=(__bf16)v.x; o[5]=(__bf16)v.y; o[6]=(__bf16)v.z; o[7]=(__bf16)v.w;
        *(bf16x8*)(Xb + i) = o;
    } else {
        int m = n - 3072;
        int z = m / 144;
        int rem = m - z * 144;
        int by = rem / 12, bx = rem % 12;
        const float* W = z == 0 ? W0 : z == 1 ? W1 : z == 2 ? W2 : W3;
        __bf16*      T = z == 0 ? T0 : z == 1 ? T1 : z == 2 ? T2 : T3;

        const int r0 = by * 64, c0 = bx * 64;
        const int lx = tid & 63, g = tid >> 6;

        #pragma unroll
        for (int rr = 0; rr < 16; ++rr) {
            int r = g * 16 + rr;
            t[r][lx] = W[(size_t)(r0 + r) * D_MODEL + c0 + lx];
        }
        __syncthreads();

        const int nn = tid >> 2;
        const int kb = (tid & 3) * 16;
        bf16x8 o1, o2;
        #pragma unroll
        for (int mm = 0; mm < 8; ++mm) o1[mm] = (__bf16)t[kb + mm][nn];
        #pragma unroll
        for (int mm = 0; mm < 8; ++mm) o2[mm] = (__bf16)t[kb + 8 + mm][nn];
        __bf16* dst = T + (size_t)(c0 + nn) * D_MODEL + r0 + kb;
        *(bf16x8*)dst       = o1;
        *(bf16x8*)(dst + 8) = o2;
    }
}

// ---------------------------------------------------------------------------
// Fused QKV projection. v9: 8-PHASE-style interleave on R7's 256x256 geometry.
// R0-R8 lesson: every 2-barrier variant (any tile / buffering / occupancy /
// regs) lands at 420+-15 TF = the catalog's measured 2-phase structural
// ceiling (stage+vmcnt+barrier ~72% of the loop, m233). The verified escape
// is the per-phase fine interleave (m196/m201). Here: BK=32, triple-buffered
// (96 KB, 1 block/CU), counted vmcnt(4) at iter top, then FOUR quadrant
// phases per K-step: {issue 1 staging gload -> ds_read 4A+2B frags ->
// setprio(1) -> 8 MFMA -> setprio(0) -> s_barrier}. Loads span phases and
// are never drained mid-loop. Restage safety: phase gloads target buffer
// (t+2)%3, last computed-from in iter t-1, sealed by iter-t's top barrier.
// acc[8][4]=128 AGPR (R7: 96 VGPR, no spill, WRITE normal). Grid 288 (9x32),
// epilogue indexing identical to R7 (numerics-verified).
// Q pre-scaled by 0.125; V written transposed as fp16 for the S^T attention.
// ---------------------------------------------------------------------------
__global__ __launch_bounds__(512, 2)
void qkv_gemm(const __bf16* __restrict__ Xb,
              const __bf16* __restrict__ Wqt, const __bf16* __restrict__ Wkt,
              const __bf16* __restrict__ Wvt,
              const float* __restrict__ bq, const float* __restrict__ bk,
              const float* __restrict__ bv,
              __bf16* __restrict__ Qb, __bf16* __restrict__ Kb,
              _Float16* __restrict__ Vtb)
{
    __shared__ bf16x8 Asf[3][16][64];   // [buf][slot][lane] 48 KB (256 rows x 32 k)
    __shared__ bf16x8 Bsf[3][16][64];   //                   48 KB (256 cols x 32 k)

    const int tid  = threadIdx.x;
    const int wv   = tid >> 6;            // 0..7
    const int ln   = tid & 63;
    const int t15  = ln & 15;
    const int quad = ln >> 4;
    const int wr = wv >> 2, wc = wv & 3;  // 2 x 4 wave grid (128x64 per wave)

    const int lin = blockIdx.x;          // 288 blocks: c*32 + r
    const int c   = lin >> 5;            // 0..8
    const int r   = lin & 31;
    const int which = c / 3;             // 0=Q 1=K 2=V  (768 = 3x256 per output)
    const int col0  = (c % 3) * 256;
    const int row0  = r * 256;

    const __bf16* Wt  = which == 0 ? Wqt : which == 1 ? Wkt : Wvt;
    const float* bias = which == 0 ? bq  : which == 1 ? bk  : bv;

    f32x4 acc[8][4];
    #pragma unroll
    for (int i = 0; i < 8; ++i)
        #pragma unroll
        for (int j = 0; j < 4; ++j) acc[i][j] = (f32x4){0.f,0.f,0.f,0.f};

    // Per K-step: 32 KB = 32 x 1KB slots (16 A slots of 16 rows + 16 B slots
    // of 16 cols). Wave wv owns ids {4wv..4wv+3}: id<16 -> A[slot=id],
    // else B[slot=id-16]. Lane l covers row/col (16*slot + t15), k 8*quad..+7.
    const __bf16* seg[4];
    bf16x8*       dstp[4];
    #pragma unroll
    for (int u = 0; u < 4; ++u) {
        const int id   = wv * 4 + u;
        const int isB  = id >> 4;
        const int slot = id & 15;
        const __bf16* base = isB
            ? Wt + (size_t)(col0 + 16 * slot + t15) * D_MODEL
            : Xb + (size_t)(row0 + 16 * slot + t15) * D_MODEL;
        seg[u]  = base + 8 * quad;
        dstp[u] = isB ? &Bsf[0][slot][0] : &Asf[0][slot][0];
    }

    auto stage_all = [&](int buf, int k0) {  // prologue only: 4 gloads at once
        #pragma unroll
        for (int u = 0; u < 4; ++u)
            gload_lds16(seg[u] + k0, dstp[u] + buf * 1024);  // buf stride = 16KB
    };

    stage_all(0, 0);
    stage_all(1, 32);                        // 8 loads in flight per wave

    const int NT = D_MODEL / 32;             // 24
    int cur = 0, nx = 2;
    for (int t = 0; t < NT; ++t) {
        if (t < NT - 1) { asm volatile("s_waitcnt vmcnt(4)" ::: "memory"); }
        else            { asm volatile("s_waitcnt vmcnt(0)" ::: "memory"); }
        __builtin_amdgcn_s_barrier();        // tile-t fully in LDS for all waves
        const bool doStage = (t + 2 < NT);
        const int  kS      = 32 * (t + 2);

        // 4 quadrant phases: rh = p>>1 (rows 4rh..4rh+3), ch = p&1 (cols 2ch..2ch+1)
        #pragma unroll
        for (int p = 0; p < 4; ++p) {
            if (doStage)
                gload_lds16(seg[p] + kS, dstp[p] + nx * 1024);  // 1 of 4 stage loads

            const int rh = p >> 1, ch = p & 1;
            bf16x8 af[4], bfr[2];
            #pragma unroll
            for (int i = 0; i < 4; ++i) af[i]  = Asf[cur][8 * wr + 4 * rh + i][ln];
            #pragma unroll
            for (int j = 0; j < 2; ++j) bfr[j] = Bsf[cur][4 * wc + 2 * ch + j][ln];

            __builtin_amdgcn_s_setprio(1);
            #pragma unroll
            for (int i = 0; i < 4; ++i)
                #pragma unroll
                for (int j = 0; j < 2; ++j)
                    acc[4 * rh + i][2 * ch + j] =
                        __builtin_amdgcn_mfma_f32_16x16x32_bf16(af[i], bfr[j],
                            acc[4 * rh + i][2 * ch + j], 0, 0, 0);
            __builtin_amdgcn_s_setprio(0);
            __builtin_amdgcn_s_barrier();    // phase boundary (keeps waves in rhythm)
        }

        cur = (cur == 2) ? 0 : cur + 1;
        nx  = (nx  == 2) ? 0 : nx  + 1;
    }

    if (which < 2) {
        const float oscale = (which == 0) ? 0.125f : 1.0f;
        __bf16* dstq = which ? Kb : Qb;
        #pragma unroll
        for (int i = 0; i < 8; ++i) {
            const int rowb = row0 + 128 * wr + 16 * i + 4 * quad;
            const int s0   = rowb & (SEQ - 1);
            #pragma unroll
            for (int j = 0; j < 4; ++j) {
                const int col = col0 + 64 * wc + 16 * j + t15;
                const float bval = bias[col];
                const int ne = col & ~1;
                const float fr = __expf((float)ne * (-9.210340371976184f / 768.0f));
                const float cf = __cosf(fr), sf = __sinf(fr);   // rotation step per row
                const float sgn = (col & 1) ? 1.0f : -1.0f;
                float ang = (float)s0 * fr;
                float ca = __cosf(ang), sa = __sinf(ang);
                #pragma unroll
                for (int rr = 0; rr < 4; ++rr) {
                    const int rw = rowb + rr;
                    float val  = acc[i][j][rr] + bval;
                    float part = __shfl_xor(val, 1, 64);
                    dstq[(size_t)rw * D_MODEL + col] = (__bf16)((val * ca + part * sgn * sa) * oscale);
                    float cn = ca * cf - sa * sf;               // advance angle by fr
                    sa = sa * cf + ca * sf;
                    ca = cn;
                }
            }
        }
    } else {
        #pragma unroll
        for (int i = 0; i < 8; ++i) {
            const int rowb = row0 + 128 * wr + 16 * i + 4 * quad;
            #pragma unroll
            for (int j = 0; j < 4; ++j) {
                const int col = col0 + 64 * wc + 16 * j + t15;
                const float bval = bias[col];
                const int h = col >> 6, d = col & 63;
                const int bidx = rowb >> 11, s = rowb & (SEQ - 1);
                f16x4 pk;
                #pragma unroll
                for (int rr = 0; rr < 4; ++rr) pk[rr] = (_Float16)(acc[i][j][rr] + bval);
                *(f16x4*)(Vtb + ((size_t)(bidx * NUM_HEADS + h) * 64 + d) * SEQ + s) = pk;
            }
        }
    }
}

// ---------------------------------------------------------------------------
// Output projection: 64x128 tile, 768 blocks. v4 (R3 winner): K_STEP=32
// triple-buffered counted-vmcnt pipeline (3 loads/wave/step -> waits 6/3/0),
// 36KB LDS + 120 regs -> 4 blocks/CU.
// ---------------------------------------------------------------------------
__global__ __launch_bounds__(256)
void out_gemm(const __bf16* __restrict__ Ab, const __bf16* __restrict__ Wt,
              const float* __restrict__ bias, float* __restrict__ Cout)
{
    __shared__ bf16x8 Asf[3][4][64];    // 12 KB (64 rows x 32 k)
    __shared__ bf16x8 Bsf[3][8][64];    // 24 KB (128 cols x 32 k)

    const int tid  = threadIdx.x;
    const int wv   = tid >> 6;
    const int ln   = tid & 63;
    const int t15  = ln & 15;
    const int quad = ln >> 4;
    const int wr = wv >> 1, wc = wv & 1;

    const int lin  = blockIdx.x;         // 768 blocks: c*128 + r
    const int col0 = (lin >> 7) * 128;
    const int row0 = (lin & 127) * 64;

    f32x4 acc[2][4];
    #pragma unroll
    for (int i = 0; i < 2; ++i)
        #pragma unroll
        for (int j = 0; j < 4; ++j) acc[i][j] = (f32x4){0.f,0.f,0.f,0.f};

    auto stage = [&](int buf, int k0) {    // 3 gload_lds per wave = 1 batch
        #pragma unroll
        for (int u = 0; u < 3; ++u) {
            const int id = wv * 3 + u;     // 0..11: 4 A slots + 8 B slots
            if (id < 4) {
                const __bf16* src = Ab + (size_t)(row0 + 16 * id + t15) * D_MODEL
                                       + k0 + 8 * quad;
                gload_lds16(src, &Asf[buf][id][0]);
            } else {
                const int w = id - 4;
                const __bf16* src = Wt + (size_t)(col0 + 16 * w + t15) * D_MODEL
                                       + k0 + 8 * quad;
                gload_lds16(src, &Bsf[buf][w][0]);
            }
        }
    };

    stage(0, 0);
    stage(1, 32);
    stage(2, 64);                          // 9 loads in flight

    const int NT = D_MODEL / 32;           // 24
    int cur = 0;
    for (int t = 0; t < NT; ++t) {
        if (t + 2 < NT)      { asm volatile("s_waitcnt vmcnt(6)" ::: "memory"); }
        else if (t + 1 < NT) { asm volatile("s_waitcnt vmcnt(3)" ::: "memory"); }
        else                 { asm volatile("s_waitcnt vmcnt(0)" ::: "memory"); }
        __builtin_amdgcn_s_barrier();

        bf16x8 af[2], bfr[4];
        #pragma unroll
        for (int i = 0; i < 2; ++i) af[i]  = Asf[cur][2 * wr + i][ln];
        #pragma unroll
        for (int j = 0; j < 4; ++j) bfr[j] = Bsf[cur][4 * wc + j][ln];
        #pragma unroll
        for (int i = 0; i < 2; ++i)
            #pragma unroll
            for (int j = 0; j < 4; ++j)
                acc[i][j] = __builtin_amdgcn_mfma_f32_16x16x32_bf16(af[i], bfr[j], acc[i][j], 0, 0, 0);

        asm volatile("s_waitcnt lgkmcnt(0)" ::: "memory");
        __builtin_amdgcn_s_barrier();
        if (t + 3 < NT) stage(cur, 32 * (t + 3));
        cur = (cur == 2) ? 0 : cur + 1;
    }

    #pragma unroll
    for (int i = 0; i < 2; ++i) {
        const int rowb = row0 + 32 * wr + 16 * i + 4 * quad;
        #pragma unroll
        for (int j = 0; j < 4; ++j) {
            const int col = col0 + 64 * wc + 16 * j + t15;
            const float bval = bias[col];
            #pragma unroll
            for (int rr = 0; rr < 4; ++rr)
                Cout[(size_t)(rowb + rr) * D_MODEL + col] = acc[i][j][rr] + bval;
        }
    }
}

// ---------------------------------------------------------------------------
// Flash attention v5 (R4 exact): S^T trick — P stays in registers, V fp16
// staged via global_load_lds, 32 KB LDS, LPT dispatch, masked skip.
// ---------------------------------------------------------------------------
__device__ __forceinline__ void attn_tile(
    const bf16x8 (*Kbuf)[64], const _Float16* Vbuf /* [8][512] */,
    bf16x8 aq0, bf16x8 aq1,
    f32x4* o, float& lacc,
    int ln, int t15, int quad, int j0, int qglob, bool domask)
{
    // S^T = K Q^T  (A = K-frag, B = Q-frag; Q pre-scaled by 1/8)
    f32x4 s[4];
    #pragma unroll
    for (int c = 0; c < 4; ++c) {
        s[c] = (f32x4){0.f, 0.f, 0.f, 0.f};
        s[c] = __builtin_amdgcn_mfma_f32_16x16x32_bf16(Kbuf[c][ln],     aq0, s[c], 0, 0, 0);
        s[c] = __builtin_amdgcn_mfma_f32_16x16x32_bf16(Kbuf[4 + c][ln], aq1, s[c], 0, 0, 0);
    }

    // p = exp(s^T); mask key>query; lane-local l; pack to fp16 A-frags
    f16x4 pf[4];
    #pragma unroll
    for (int c = 0; c < 4; ++c)
        #pragma unroll
        for (int r = 0; r < 4; ++r) {
            float e = __expf(s[c][r]);
            if (domask && (j0 + 16 * c + 4 * quad + r > qglob)) e = 0.f;
            lacc += e;
            pf[c][r] = (_Float16)e;
        }

    // O^acc += P V : 16x16x16 f16 MFMA, P from registers, V frag = ds_read_b64
    #pragma unroll
    for (int c = 0; c < 4; ++c) {
        const int lv = 16 * (2 * (c & 1) + (quad >> 1)) + t15;
        const int jb = 4 * (quad & 1);
        #pragma unroll
        for (int cd = 0; cd < 4; ++cd) {
            f16x4 vf = *(const f16x4*)&Vbuf[(size_t)(4 * (c >> 1) + cd) * 512 + lv * 8 + jb];
            o[cd] = __builtin_amdgcn_mfma_f32_16x16x16f16(pf[c], vf, o[cd], 0, 0, 0);
        }
    }
}

__global__ __launch_bounds__(512)
void attn_flash(const __bf16* __restrict__ Q, const __bf16* __restrict__ K,
                const _Float16* __restrict__ Vt, __bf16* __restrict__ O)
{
    __shared__ bf16x8   Kf[2][8][64];   // 16 KB (double-buffered)
    __shared__ _Float16 Vh[2][8][512];  // 16 KB

    const int tid  = threadIdx.x;
    const int wv   = tid >> 6;
    const int ln   = tid & 63;
    const int t15  = ln & 15;
    const int quad = ln >> 4;

    const int n  = blockIdx.x;          // LPT: longest q-tiles first
    const int qt = 15 - (n / 48);
    const int bh = n % 48;
    const int b  = bh / NUM_HEADS;
    const int h  = bh % NUM_HEADS;
    const int q0 = qt * 128;
    const int nt = (q0 >> 6) + 2;

    bf16x8 aq0, aq1;
    {
        const __bf16* qs = Q + (size_t)(b * SEQ + q0 + 16 * wv + t15) * D_MODEL + h * 64 + 8 * quad;
        aq0 = *(const bf16x8*)qs;
        aq1 = *(const bf16x8*)(qs + 32);
    }

    const __bf16*   kp = K  + ((size_t)b * SEQ + 16 * (wv & 3) + t15) * D_MODEL
                            + h * 64 + 32 * (wv >> 2) + 8 * quad;
    const _Float16* vp = Vt + ((size_t)bh * 64 + 16 * (wv & 3) + t15) * SEQ
                            + 32 * (wv >> 2) + 8 * quad;

    f32x4 o[4];
    #pragma unroll
    for (int c = 0; c < 4; ++c) o[c] = (f32x4){0.f,0.f,0.f,0.f};
    float lacc = 0.f;
    const int qglob = q0 + 16 * wv + t15;   // this lane's query row
    const int wmax  = q0 + 16 * wv + 15;    // wave's last query row

    gload_lds16(kp, &Kf[0][wv][0]);
    gload_lds16(vp, &Vh[0][wv][0]);

    int cur = 0;
    for (int it = 0; it < nt; ++it) {
        __syncthreads();
        if (it + 1 < nt) {
            const int jn = (it + 1) * 64;
            gload_lds16(kp + (size_t)jn * D_MODEL, &Kf[cur ^ 1][wv][0]);
            gload_lds16(vp + jn,                   &Vh[cur ^ 1][wv][0]);
        }
        const int j0 = it * 64;
        if (j0 <= wmax) {                // skip fully-masked tiles
            const bool domask = (j0 + 63) > (q0 + 16 * wv);
            attn_tile(Kf[cur], &Vh[cur][0][0], aq0, aq1, o, lacc,
                      ln, t15, quad, j0, qglob, domask);
        }
        cur ^= 1;
    }

    // l per lane (query = t15): reduce over quads, redistribute to C-layout rows
    lacc += __shfl_xor(lacc, 16, 64);
    lacc += __shfl_xor(lacc, 32, 64);

    float inv[4];
    #pragma unroll
    for (int r = 0; r < 4; ++r)
        inv[r] = 1.0f / __shfl(lacc, 4 * quad + r, 64);

    #pragma unroll
    for (int c = 0; c < 4; ++c)
        #pragma unroll
        for (int r = 0; r < 4; ++r) {
            int row = q0 + 16 * wv + 4 * quad + r;
            O[(size_t)(b * SEQ + row) * D_MODEL + h * 64 + 16 * c + t15] = (__bf16)(o[c][r] * inv[r]);
        }
}

// ---------------------------------------------------------------------------
extern "C" void kernel_launch(void* const* d_in, const int* in_sizes, int n_in,
                              void* d_out, int out_size, void* d_ws, size_t ws_size,
                              hipStream_t stream) {
    const float* X  = (const float*)d_in[0];
    const float* Wq = (const float*)d_in[1];
    const float* bq = (const float*)d_in[2];
    const float* Wk = (const float*)d_in[3];
    const float* bk = (const float*)d_in[4];
    const float* Wv = (const float*)d_in[5];
    const float* bv = (const float*)d_in[6];
    const float* Wo = (const float*)d_in[7];
    const float* bo = (const float*)d_in[8];
    float* out = (float*)d_out;

    const size_t BSD = (size_t)MROWS * D_MODEL;   // 6,291,456
    const size_t WSZ = (size_t)D_MODEL * D_MODEL; //   589,824

    __bf16*   Xb  = (__bf16*)d_ws;
    __bf16*   Qb  = Xb  + BSD;
    __bf16*   Kb  = Qb  + BSD;
    _Float16* Vtb = (_Float16*)(Kb + BSD);
    __bf16*   Ob  = (__bf16*)(Vtb + BSD);
    __bf16*   Wqt = Ob  + BSD;
    __bf16*   Wkt = Wqt + WSZ;
    __bf16*   Wvt = Wkt + WSZ;
    __bf16*   Wot = Wvt + WSZ;

    prep<<<3648, 256, 0, stream>>>(X, Xb, Wq, Wk, Wv, Wo, Wqt, Wkt, Wvt, Wot);

    qkv_gemm<<<288, 512, 0, stream>>>(Xb, Wqt, Wkt, Wvt, bq, bk, bv, Qb, Kb, Vtb);

    attn_flash<<<768, 512, 0, stream>>>(Qb, Kb, Vtb, Ob);

    out_gemm<<<768, 256, 0, stream>>>(Ob, Wot, bo, out);
}

// Round 10
// 231.333 us; speedup vs baseline: 1.0180x; 1.0180x over previous
//
#include <hip/hip_runtime.h>
#include <math.h>

#define D_MODEL 768
#define NUM_HEADS 12
#define HEAD_DIM 64
#define SEQ 2048
#define BATCH 4
#define MROWS (BATCH * SEQ)   // 8192
#define HALF_D (D_MODEL / 2)  // 384

typedef __bf16    bf16x8 __attribute__((ext_vector_type(8)));
typedef _Float16  f16x4  __attribute__((ext_vector_type(4)));
typedef float     f32x4  __attribute__((ext_vector_type(4)));

// async global->LDS, 16B per lane; LDS dest = wave-uniform base + lane*16
__device__ __forceinline__ void gload_lds16(const void* gp, void* lp) {
    __builtin_amdgcn_global_load_lds(
        (const __attribute__((address_space(1))) unsigned int*)gp,
        (__attribute__((address_space(3))) unsigned int*)lp, 16, 0, 0);
}

// ---------------------------------------------------------------------------
// prep: X cast (blocks [0,3072)) + weight cast/transpose ([3072,3648)).
// ---------------------------------------------------------------------------
__global__ __launch_bounds__(256)
void prep(const float* __restrict__ X, __bf16* __restrict__ Xb,
          const float* __restrict__ W0, const float* __restrict__ W1,
          const float* __restrict__ W2, const float* __restrict__ W3,
          __bf16* __restrict__ T0, __bf16* __restrict__ T1,
          __bf16* __restrict__ T2, __bf16* __restrict__ T3)
{
    __shared__ float t[64][65];
    const int n   = blockIdx.x;
    const int tid = threadIdx.x;

    if (n < 3072) {
        size_t i = ((size_t)n * 256 + tid) * 8;
        float4 u = *(const float4*)(X + i);
        float4 v = *(const float4*)(X + i + 4);
        bf16x8 o;
        o[0]=(__bf16)u.x; o[1]=(__bf16)u.y; o[2]=(__bf16)u.z; o[3]=(__bf16)u.w;
        o[4]=(__bf16)v.x; o[5]=(__bf16)v.y; o[6]=(__bf16)v.z; o[7]=(__bf16)v.w;
        *(bf16x8*)(Xb + i) = o;
    } else {
        int m = n - 3072;
        int z = m / 144;
        int rem = m - z * 144;
        int by = rem / 12, bx = rem % 12;
        const float* W = z == 0 ? W0 : z == 1 ? W1 : z == 2 ? W2 : W3;
        __bf16*      T = z == 0 ? T0 : z == 1 ? T1 : z == 2 ? T2 : T3;

        const int r0 = by * 64, c0 = bx * 64;
        const int lx = tid & 63, g = tid >> 6;

        #pragma unroll
        for (int rr = 0; rr < 16; ++rr) {
            int r = g * 16 + rr;
            t[r][lx] = W[(size_t)(r0 + r) * D_MODEL + c0 + lx];
        }
        __syncthreads();

        const int nn = tid >> 2;
        const int kb = (tid & 3) * 16;
        bf16x8 o1, o2;
        #pragma unroll
        for (int mm = 0; mm < 8; ++mm) o1[mm] = (__bf16)t[kb + mm][nn];
        #pragma unroll
        for (int mm = 0; mm < 8; ++mm) o2[mm] = (__bf16)t[kb + 8 + mm][nn];
        __bf16* dst = T + (size_t)(c0 + nn) * D_MODEL + r0 + kb;
        *(bf16x8*)dst       = o1;
        *(bf16x8*)(dst + 8) = o2;
    }
}

// ---------------------------------------------------------------------------
// Fused QKV projection. v9 (R9, kept): 256x256 tile, BK=32, triple-buffered
// counted-vmcnt, 4 quadrant phases per K-step. qkv is at its practical
// structural limit in plain HIP (R0-R9: ten variants spanning tile/K-step/
// buffering/occupancy/phase-split all land at 68-75us, ~420 TF — the
// documented 2-phase-family ceiling; the full 8-phase escape needs the
// derived-waits machinery that did not reproduce here, matching m232 OPEN).
// Q pre-scaled by 0.125; V written transposed as fp16 for the S^T attention.
// ---------------------------------------------------------------------------
__global__ __launch_bounds__(512, 2)
void qkv_gemm(const __bf16* __restrict__ Xb,
              const __bf16* __restrict__ Wqt, const __bf16* __restrict__ Wkt,
              const __bf16* __restrict__ Wvt,
              const float* __restrict__ bq, const float* __restrict__ bk,
              const float* __restrict__ bv,
              __bf16* __restrict__ Qb, __bf16* __restrict__ Kb,
              _Float16* __restrict__ Vtb)
{
    __shared__ bf16x8 Asf[3][16][64];   // [buf][slot][lane] 48 KB (256 rows x 32 k)
    __shared__ bf16x8 Bsf[3][16][64];   //                   48 KB (256 cols x 32 k)

    const int tid  = threadIdx.x;
    const int wv   = tid >> 6;            // 0..7
    const int ln   = tid & 63;
    const int t15  = ln & 15;
    const int quad = ln >> 4;
    const int wr = wv >> 2, wc = wv & 3;  // 2 x 4 wave grid (128x64 per wave)

    const int lin = blockIdx.x;          // 288 blocks: c*32 + r
    const int c   = lin >> 5;            // 0..8
    const int r   = lin & 31;
    const int which = c / 3;             // 0=Q 1=K 2=V  (768 = 3x256 per output)
    const int col0  = (c % 3) * 256;
    const int row0  = r * 256;

    const __bf16* Wt  = which == 0 ? Wqt : which == 1 ? Wkt : Wvt;
    const float* bias = which == 0 ? bq  : which == 1 ? bk  : bv;

    f32x4 acc[8][4];
    #pragma unroll
    for (int i = 0; i < 8; ++i)
        #pragma unroll
        for (int j = 0; j < 4; ++j) acc[i][j] = (f32x4){0.f,0.f,0.f,0.f};

    const __bf16* seg[4];
    bf16x8*       dstp[4];
    #pragma unroll
    for (int u = 0; u < 4; ++u) {
        const int id   = wv * 4 + u;
        const int isB  = id >> 4;
        const int slot = id & 15;
        const __bf16* base = isB
            ? Wt + (size_t)(col0 + 16 * slot + t15) * D_MODEL
            : Xb + (size_t)(row0 + 16 * slot + t15) * D_MODEL;
        seg[u]  = base + 8 * quad;
        dstp[u] = isB ? &Bsf[0][slot][0] : &Asf[0][slot][0];
    }

    auto stage_all = [&](int buf, int k0) {  // prologue only: 4 gloads at once
        #pragma unroll
        for (int u = 0; u < 4; ++u)
            gload_lds16(seg[u] + k0, dstp[u] + buf * 1024);  // buf stride = 16KB
    };

    stage_all(0, 0);
    stage_all(1, 32);                        // 8 loads in flight per wave

    const int NT = D_MODEL / 32;             // 24
    int cur = 0, nx = 2;
    for (int t = 0; t < NT; ++t) {
        if (t < NT - 1) { asm volatile("s_waitcnt vmcnt(4)" ::: "memory"); }
        else            { asm volatile("s_waitcnt vmcnt(0)" ::: "memory"); }
        __builtin_amdgcn_s_barrier();        // tile-t fully in LDS for all waves
        const bool doStage = (t + 2 < NT);
        const int  kS      = 32 * (t + 2);

        // 4 quadrant phases: rh = p>>1 (rows 4rh..4rh+3), ch = p&1 (cols 2ch..2ch+1)
        #pragma unroll
        for (int p = 0; p < 4; ++p) {
            if (doStage)
                gload_lds16(seg[p] + kS, dstp[p] + nx * 1024);  // 1 of 4 stage loads

            const int rh = p >> 1, ch = p & 1;
            bf16x8 af[4], bfr[2];
            #pragma unroll
            for (int i = 0; i < 4; ++i) af[i]  = Asf[cur][8 * wr + 4 * rh + i][ln];
            #pragma unroll
            for (int j = 0; j < 2; ++j) bfr[j] = Bsf[cur][4 * wc + 2 * ch + j][ln];

            __builtin_amdgcn_s_setprio(1);
            #pragma unroll
            for (int i = 0; i < 4; ++i)
                #pragma unroll
                for (int j = 0; j < 2; ++j)
                    acc[4 * rh + i][2 * ch + j] =
                        __builtin_amdgcn_mfma_f32_16x16x32_bf16(af[i], bfr[j],
                            acc[4 * rh + i][2 * ch + j], 0, 0, 0);
            __builtin_amdgcn_s_setprio(0);
            __builtin_amdgcn_s_barrier();    // phase boundary (keeps waves in rhythm)
        }

        cur = (cur == 2) ? 0 : cur + 1;
        nx  = (nx  == 2) ? 0 : nx  + 1;
    }

    if (which < 2) {
        const float oscale = (which == 0) ? 0.125f : 1.0f;
        __bf16* dstq = which ? Kb : Qb;
        #pragma unroll
        for (int i = 0; i < 8; ++i) {
            const int rowb = row0 + 128 * wr + 16 * i + 4 * quad;
            const int s0   = rowb & (SEQ - 1);
            #pragma unroll
            for (int j = 0; j < 4; ++j) {
                const int col = col0 + 64 * wc + 16 * j + t15;
                const float bval = bias[col];
                const int ne = col & ~1;
                const float fr = __expf((float)ne * (-9.210340371976184f / 768.0f));
                const float cf = __cosf(fr), sf = __sinf(fr);   // rotation step per row
                const float sgn = (col & 1) ? 1.0f : -1.0f;
                float ang = (float)s0 * fr;
                float ca = __cosf(ang), sa = __sinf(ang);
                #pragma unroll
                for (int rr = 0; rr < 4; ++rr) {
                    const int rw = rowb + rr;
                    float val  = acc[i][j][rr] + bval;
                    float part = __shfl_xor(val, 1, 64);
                    dstq[(size_t)rw * D_MODEL + col] = (__bf16)((val * ca + part * sgn * sa) * oscale);
                    float cn = ca * cf - sa * sf;               // advance angle by fr
                    sa = sa * cf + ca * sf;
                    ca = cn;
                }
            }
        }
    } else {
        #pragma unroll
        for (int i = 0; i < 8; ++i) {
            const int rowb = row0 + 128 * wr + 16 * i + 4 * quad;
            #pragma unroll
            for (int j = 0; j < 4; ++j) {
                const int col = col0 + 64 * wc + 16 * j + t15;
                const float bval = bias[col];
                const int h = col >> 6, d = col & 63;
                const int bidx = rowb >> 11, s = rowb & (SEQ - 1);
                f16x4 pk;
                #pragma unroll
                for (int rr = 0; rr < 4; ++rr) pk[rr] = (_Float16)(acc[i][j][rr] + bval);
                *(f16x4*)(Vtb + ((size_t)(bidx * NUM_HEADS + h) * 64 + d) * SEQ + s) = pk;
            }
        }
    }
}

// ---------------------------------------------------------------------------
// Output projection v5: 128x192 tile -> grid 64x4 = 256 blocks = EXACTLY 1/CU
// (zero tail), 512 threads / 8 waves (2x4), per-wave 64x48, acc[4][3]=48 AGPR.
// Intensity up from 6 ds_reads/8 MFMA (64x128) to 7/12 (R7 lesson: bigger
// tile improves per-MFMA throughput; R8 lesson: grid must divide 256).
// R6-proven skeleton: BK=32, triple-buffered (60 KB), ONE barrier per step,
// counted vmcnt — 20 staging segs/step: waves 0-3 own 3, waves 4-7 own 2 ->
// per-wave steady wait vmcnt(3)/vmcnt(2), drained to 0 only at the tail.
// ---------------------------------------------------------------------------
__global__ __launch_bounds__(512, 2)
void out_gemm(const __bf16* __restrict__ Ab, const __bf16* __restrict__ Wt,
              const float* __restrict__ bias, float* __restrict__ Cout)
{
    __shared__ bf16x8 Asf[3][8][64];    // 24 KB (128 rows x 32 k)
    __shared__ bf16x8 Bsf[3][12][64];   // 36 KB (192 cols x 32 k)

    const int tid  = threadIdx.x;
    const int wv   = tid >> 6;            // 0..7
    const int ln   = tid & 63;
    const int t15  = ln & 15;
    const int quad = ln >> 4;
    const int wr = wv >> 2, wc = wv & 3;  // 2 x 4 wave grid (64x48 per wave)

    const int lin  = blockIdx.x;          // 256 blocks: ct*64 + rt
    const int col0 = (lin >> 6) * 192;    // 4 col tiles
    const int row0 = (lin & 63) * 128;    // 64 row tiles

    f32x4 acc[4][3];
    #pragma unroll
    for (int i = 0; i < 4; ++i)
        #pragma unroll
        for (int j = 0; j < 3; ++j) acc[i][j] = (f32x4){0.f,0.f,0.f,0.f};

    // Per K32-step: 20 x 1KB segments (8 A slots of 16 rows + 12 B slots of
    // 16 cols). Waves 0-3 own ids {3wv..3wv+2}; waves 4-7 own {12+2(wv-4), +1}.
    const int base = (wv < 4) ? wv * 3 : 12 + (wv - 4) * 2;
    const int nseg = (wv < 4) ? 3 : 2;
    const __bf16* seg[3];
    bf16x8*       dstp[3];
    int           bstr[3];
    #pragma unroll
    for (int u = 0; u < 3; ++u) {
        const int id   = base + ((u < nseg) ? u : 0);   // dup for unused slot
        const int isB  = id >= 8;
        const int slot = isB ? id - 8 : id;
        const __bf16* bb = isB
            ? Wt + (size_t)(col0 + 16 * slot + t15) * D_MODEL
            : Ab + (size_t)(row0 + 16 * slot + t15) * D_MODEL;
        seg[u]  = bb + 8 * quad;
        dstp[u] = isB ? &Bsf[0][slot][0] : &Asf[0][slot][0];
        bstr[u] = isB ? 12 * 64 : 8 * 64;   // per-buffer stride in bf16x8 units
    }

    auto stage = [&](int buf, int k0) {     // nseg gloads per wave = 1 batch
        #pragma unroll
        for (int u = 0; u < 3; ++u)
            if (u < nseg)
                gload_lds16(seg[u] + k0, dstp[u] + buf * bstr[u]);
    };

    stage(0, 0);
    stage(1, 32);                            // 2*nseg loads in flight per wave

    const int NT = D_MODEL / 32;             // 24
    int cur = 0, nx = 2;
    for (int t = 0; t < NT; ++t) {
        if (t < NT - 1) {
            if (wv < 4) { asm volatile("s_waitcnt vmcnt(3)" ::: "memory"); }
            else        { asm volatile("s_waitcnt vmcnt(2)" ::: "memory"); }
        } else          { asm volatile("s_waitcnt vmcnt(0)" ::: "memory"); }
        __builtin_amdgcn_s_barrier();        // batch-t in LDS for all waves;
                                             // also proves compute(t-1) done
        if (t + 2 < NT) stage(nx, 32 * (t + 2));

        bf16x8 af[4], bfr[3];
        #pragma unroll
        for (int i = 0; i < 4; ++i) af[i]  = Asf[cur][4 * wr + i][ln];
        #pragma unroll
        for (int j = 0; j < 3; ++j) bfr[j] = Bsf[cur][3 * wc + j][ln];
        #pragma unroll
        for (int i = 0; i < 4; ++i)
            #pragma unroll
            for (int j = 0; j < 3; ++j)
                acc[i][j] = __builtin_amdgcn_mfma_f32_16x16x32_bf16(af[i], bfr[j], acc[i][j], 0, 0, 0);

        cur = (cur == 2) ? 0 : cur + 1;
        nx  = (nx  == 2) ? 0 : nx  + 1;
    }

    #pragma unroll
    for (int i = 0; i < 4; ++i) {
        const int rowb = row0 + 64 * wr + 16 * i + 4 * quad;
        #pragma unroll
        for (int j = 0; j < 3; ++j) {
            const int col = col0 + 48 * wc + 16 * j + t15;
            const float bval = bias[col];
            #pragma unroll
            for (int rr = 0; rr < 4; ++rr)
                Cout[(size_t)(rowb + rr) * D_MODEL + col] = acc[i][j][rr] + bval;
        }
    }
}

// ---------------------------------------------------------------------------
// Flash attention v5 (R4 exact): S^T trick — P stays in registers, V fp16
// staged via global_load_lds, 32 KB LDS, LPT dispatch, masked skip.
// ---------------------------------------------------------------------------
__device__ __forceinline__ void attn_tile(
    const bf16x8 (*Kbuf)[64], const _Float16* Vbuf /* [8][512] */,
    bf16x8 aq0, bf16x8 aq1,
    f32x4* o, float& lacc,
    int ln, int t15, int quad, int j0, int qglob, bool domask)
{
    // S^T = K Q^T  (A = K-frag, B = Q-frag; Q pre-scaled by 1/8)
    f32x4 s[4];
    #pragma unroll
    for (int c = 0; c < 4; ++c) {
        s[c] = (f32x4){0.f, 0.f, 0.f, 0.f};
        s[c] = __builtin_amdgcn_mfma_f32_16x16x32_bf16(Kbuf[c][ln],     aq0, s[c], 0, 0, 0);
        s[c] = __builtin_amdgcn_mfma_f32_16x16x32_bf16(Kbuf[4 + c][ln], aq1, s[c], 0, 0, 0);
    }

    // p = exp(s^T); mask key>query; lane-local l; pack to fp16 A-frags
    f16x4 pf[4];
    #pragma unroll
    for (int c = 0; c < 4; ++c)
        #pragma unroll
        for (int r = 0; r < 4; ++r) {
            float e = __expf(s[c][r]);
            if (domask && (j0 + 16 * c + 4 * quad + r > qglob)) e = 0.f;
            lacc += e;
            pf[c][r] = (_Float16)e;
        }

    // O^acc += P V : 16x16x16 f16 MFMA, P from registers, V frag = ds_read_b64
    #pragma unroll
    for (int c = 0; c < 4; ++c) {
        const int lv = 16 * (2 * (c & 1) + (quad >> 1)) + t15;
        const int jb = 4 * (quad & 1);
        #pragma unroll
        for (int cd = 0; cd < 4; ++cd) {
            f16x4 vf = *(const f16x4*)&Vbuf[(size_t)(4 * (c >> 1) + cd) * 512 + lv * 8 + jb];
            o[cd] = __builtin_amdgcn_mfma_f32_16x16x16f16(pf[c], vf, o[cd], 0, 0, 0);
        }
    }
}

__global__ __launch_bounds__(512)
void attn_flash(const __bf16* __restrict__ Q, const __bf16* __restrict__ K,
                const _Float16* __restrict__ Vt, __bf16* __restrict__ O)
{
    __shared__ bf16x8   Kf[2][8][64];   // 16 KB (double-buffered)
    __shared__ _Float16 Vh[2][8][512];  // 16 KB

    const int tid  = threadIdx.x;
    const int wv   = tid >> 6;
    const int ln   = tid & 63;
    const int t15  = ln & 15;
    const int quad = ln >> 4;

    const int n  = blockIdx.x;          // LPT: longest q-tiles first
    const int qt = 15 - (n / 48);
    const int bh = n % 48;
    const int b  = bh / NUM_HEADS;
    const int h  = bh % NUM_HEADS;
    const int q0 = qt * 128;
    const int nt = (q0 >> 6) + 2;

    bf16x8 aq0, aq1;
    {
        const __bf16* qs = Q + (size_t)(b * SEQ + q0 + 16 * wv + t15) * D_MODEL + h * 64 + 8 * quad;
        aq0 = *(const bf16x8*)qs;
        aq1 = *(const bf16x8*)(qs + 32);
    }

    const __bf16*   kp = K  + ((size_t)b * SEQ + 16 * (wv & 3) + t15) * D_MODEL
                            + h * 64 + 32 * (wv >> 2) + 8 * quad;
    const _Float16* vp = Vt + ((size_t)bh * 64 + 16 * (wv & 3) + t15) * SEQ
                            + 32 * (wv >> 2) + 8 * quad;

    f32x4 o[4];
    #pragma unroll
    for (int c = 0; c < 4; ++c) o[c] = (f32x4){0.f,0.f,0.f,0.f};
    float lacc = 0.f;
    const int qglob = q0 + 16 * wv + t15;   // this lane's query row
    const int wmax  = q0 + 16 * wv + 15;    // wave's last query row

    gload_lds16(kp, &Kf[0][wv][0]);
    gload_lds16(vp, &Vh[0][wv][0]);

    int cur = 0;
    for (int it = 0; it < nt; ++it) {
        __syncthreads();
        if (it + 1 < nt) {
            const int jn = (it + 1) * 64;
            gload_lds16(kp + (size_t)jn * D_MODEL, &Kf[cur ^ 1][wv][0]);
            gload_lds16(vp + jn,                   &Vh[cur ^ 1][wv][0]);
        }
        const int j0 = it * 64;
        if (j0 <= wmax) {                // skip fully-masked tiles
            const bool domask = (j0 + 63) > (q0 + 16 * wv);
            attn_tile(Kf[cur], &Vh[cur][0][0], aq0, aq1, o, lacc,
                      ln, t15, quad, j0, qglob, domask);
        }
        cur ^= 1;
    }

    // l per lane (query = t15): reduce over quads, redistribute to C-layout rows
    lacc += __shfl_xor(lacc, 16, 64);
    lacc += __shfl_xor(lacc, 32, 64);

    float inv[4];
    #pragma unroll
    for (int r = 0; r < 4; ++r)
        inv[r] = 1.0f / __shfl(lacc, 4 * quad + r, 64);

    #pragma unroll
    for (int c = 0; c < 4; ++c)
        #pragma unroll
        for (int r = 0; r < 4; ++r) {
            int row = q0 + 16 * wv + 4 * quad + r;
            O[(size_t)(b * SEQ + row) * D_MODEL + h * 64 + 16 * c + t15] = (__bf16)(o[c][r] * inv[r]);
        }
}

// ---------------------------------------------------------------------------
extern "C" void kernel_launch(void* const* d_in, const int* in_sizes, int n_in,
                              void* d_out, int out_size, void* d_ws, size_t ws_size,
                              hipStream_t stream) {
    const float* X  = (const float*)d_in[0];
    const float* Wq = (const float*)d_in[1];
    const float* bq = (const float*)d_in[2];
    const float* Wk = (const float*)d_in[3];
    const float* bk = (const float*)d_in[4];
    const float* Wv = (const float*)d_in[5];
    const float* bv = (const float*)d_in[6];
    const float* Wo = (const float*)d_in[7];
    const float* bo = (const float*)d_in[8];
    float* out = (float*)d_out;

    const size_t BSD = (size_t)MROWS * D_MODEL;   // 6,291,456
    const size_t WSZ = (size_t)D_MODEL * D_MODEL; //   589,824

    __bf16*   Xb  = (__bf16*)d_ws;
    __bf16*   Qb  = Xb  + BSD;
    __bf16*   Kb  = Qb  + BSD;
    _Float16* Vtb = (_Float16*)(Kb + BSD);
    __bf16*   Ob  = (__bf16*)(Vtb + BSD);
    __bf16*   Wqt = Ob  + BSD;
    __bf16*   Wkt = Wqt + WSZ;
    __bf16*   Wvt = Wkt + WSZ;
    __bf16*   Wot = Wvt + WSZ;

    prep<<<3648, 256, 0, stream>>>(X, Xb, Wq, Wk, Wv, Wo, Wqt, Wkt, Wvt, Wot);

    qkv_gemm<<<288, 512, 0, stream>>>(Xb, Wqt, Wkt, Wvt, bq, bk, bv, Qb, Kb, Vtb);

    attn_flash<<<768, 512, 0, stream>>>(Qb, Kb, Vtb, Ob);

    out_gemm<<<256, 512, 0, stream>>>(Ob, Wot, bo, out);
}